// Round 14
// baseline (142.225 us; speedup 1.0000x reference)
//
#include <hip/hip_runtime.h>
#include <hip/hip_bf16.h>

#define NXC 440
#define NYC 500
#define GCELLS (NXC * NYC)              // 220000 (NZ = 1)
#define NWORDS ((GCELLS + 31) / 32)     // 6875 bitmap words (6875*32 == 220000)
#define MAXV 40000
#define MAXP 32
#define SCANB ((NWORDS + 255) / 256)    // 27 blocks for word-sliced scan
#define TPAD 4                          // ticket stride (ints): 4 counters / 64B line
#define CELLG 512                       // k_cell blocks (1024 thr, streaming)
#define ZEROB 64                        // k_zero blocks (cellflag + ticket, 0.86 MB)
#define NFLAGI (GCELLS / 4)             // cellflag as ints (220000 % 16 == 0)
#define RECI 8                          // seg record stride (ints): idx + 5 feats, 32B
#define FVOX 8                          // k_fill voxels per block (512 threads)

// Expected outputs are bf16-quantized but stored as fp32: round-trip.
__device__ __forceinline__ float bf16r(float x) {
    return __bfloat162float(__float2bfloat16(x));
}

// Linear cell index exactly as the reference (fp32 ops). Invalid -> -1.
__device__ __forceinline__ int cell_of(float x, float y, float z) {
    bool valid = (x >= 0.0f) && (x < 70.4f) &&
                 (y >= -40.0f) && (y < 40.0f) &&
                 (z >= -3.0f) && (z < 1.0f);
    if (!valid) return -1;
    int cx = (int)floorf(x / 0.16f);
    int cy = (int)floorf((y + 40.0f) / 0.16f);
    // z in [-3,1) -> cz == 0 always (NZ = 1)
    cx = min(max(cx, 0), NXC - 1);
    cy = min(max(cy, 0), NYC - 1);
    return cy * NXC + cx;
}

// LSBs of the 4 bytes of u -> nibble (byte j -> bit j).
__device__ __forceinline__ unsigned nib4(unsigned u) {
    return (u | (u >> 7) | (u >> 14) | (u >> 21)) & 0xFu;
}

// Static-index access into a float4[10] register block (unroll-only: i must
// fold to a constant so SROA keeps it in VGPRs -- no scratch).
__device__ __forceinline__ float fget(const float4 (&r)[10], int i) {
    switch (i & 3) {
        case 0:  return r[i >> 2].x;
        case 1:  return r[i >> 2].y;
        case 2:  return r[i >> 2].z;
        default: return r[i >> 2].w;
    }
}

// Zero cellflag (220 KB) + ticket (640 KB); both consumed downstream.
__global__ __launch_bounds__(256) void k_zero(unsigned* cellflag, int* ticket) {
    int tid = blockIdx.x * 256 + threadIdx.x;
    int stride = ZEROB * 256;
    uint4* f4 = (uint4*)cellflag;
    for (int i = tid; i < NFLAGI / 4; i += stride)
        f4[i] = make_uint4(0u, 0u, 0u, 0u);
    int4* t4 = (int4*)ticket;
    for (int i = tid; i < MAXV * TPAD / 4; i += stride)
        t4[i] = make_int4(0, 0, 0, 0);
}

// Pass 1: pure flag stream -- plain byte store cellflag[cell]=1 (idempotent
// race; byte-granular dirty masks, verified R10-R12 absmax=0). No cellid
// write: k_scatter recomputes cells from pts (L3-hot re-read).
__global__ __launch_bounds__(1024) void k_cell(const float* pts,
                                               unsigned char* cellflag, int n) {
    int tid = blockIdx.x * 1024 + threadIdx.x;
    int nq = n >> 2;                    // groups of 4 points
    int stride = CELLG * 1024;
    const float4* p4 = (const float4*)pts;
    for (int q = tid; q < nq; q += stride) {
        float4 f0 = p4[q * 5 + 0];      // floats 0..3   (pt0 xyzw0)
        float4 f1 = p4[q * 5 + 1];      // floats 4..7
        float4 f2 = p4[q * 5 + 2];      // floats 8..11
        float4 f3 = p4[q * 5 + 3];      // floats 12..15
        float4 f4 = p4[q * 5 + 4];      // floats 16..19
        int c0 = cell_of(f0.x, f0.y, f0.z);   // floats 0,1,2
        int c1 = cell_of(f1.y, f1.z, f1.w);   // floats 5,6,7
        int c2 = cell_of(f2.z, f2.w, f3.x);   // floats 10,11,12
        int c3 = cell_of(f3.w, f4.x, f4.y);   // floats 15,16,17
        if (c0 >= 0) cellflag[c0] = 1;
        if (c1 >= 0) cellflag[c1] = 1;
        if (c2 >= 0) cellflag[c2] = 1;
        if (c3 >= 0) cellflag[c3] = 1;
    }
    // tail (n % 4 != 0): handled scalar by one thread
    if (tid == 0) {
        for (int i = nq * 4; i < n; ++i) {
            const float* p = pts + (size_t)i * 5;
            int c = cell_of(p[0], p[1], p[2]);
            if (c >= 0) cellflag[c] = 1;
        }
    }
}

// Word-level exclusive scan over the byte-flag array (packed 32 bytes ->
// 1 word on the fly). Self-computed cross-block base -> fused
// (prefix, occword) int2 table; emit coords.
__global__ __launch_bounds__(256) void k_scan(const unsigned* cellflag,
                                              int2* wp2, float* out_coords) {
    int b = blockIdx.x, t = threadIdx.x;
    // cross-block base: count of set flags before this block's slice
    __shared__ int sb[256];
    int pre = 0;
    const uint4* f4 = (const uint4*)cellflag;   // 16 cells per uint4
    for (int i = t; i < b * 512; i += 256) {    // b*512 uint4 = b*256 words
        uint4 v = f4[i];
        unsigned s = v.x + v.y + v.z + v.w;     // per-byte sums <= 4: no carry
        pre += (int)((s * 0x01010101u) >> 24);  // sum of 4 byte-sums
    }
    sb[t] = pre;
    __syncthreads();
    for (int d = 128; d > 0; d >>= 1) {
        if (t < d) sb[t] += sb[t + d];
        __syncthreads();
    }
    int base = sb[0];
    // intra-block scan over this slice
    int w = b * 256 + t;
    unsigned o = 0u;
    if (w < NWORDS) {
        uint4 q0 = f4[w * 2], q1 = f4[w * 2 + 1];   // 32 bytes of word w
        o =  nib4(q0.x)        | (nib4(q0.y) << 4)  |
            (nib4(q0.z) << 8)  | (nib4(q0.w) << 12) |
            (nib4(q1.x) << 16) | (nib4(q1.y) << 20) |
            (nib4(q1.z) << 24) | (nib4(q1.w) << 28);
    }
    int c = __popc(o);
    __shared__ int s[256];
    s[t] = c;
    __syncthreads();
    for (int d = 1; d < 256; d <<= 1) {
        int v = (t >= d) ? s[t - d] : 0;
        __syncthreads();
        s[t] += v;
        __syncthreads();
    }
    int vid = base + (s[t] - c);
    if (w < NWORDS) {
        wp2[w] = make_int2(vid, (int)o);
        if (vid < MAXV) {
            unsigned m = o;
            while (m) {
                int bit = __ffs(m) - 1;
                m &= m - 1u;
                if (vid < MAXV) {
                    int cell = w * 32 + bit;
                    int cy = cell / NXC, cx = cell - cy * NXC;
                    float* oc = out_coords + (size_t)vid * 3;
                    oc[0] = 0.0f;
                    oc[1] = bf16r((float)cy);
                    oc[2] = bf16r((float)cx);
                }
                ++vid;
            }
        }
    }
}

// Ticket + 32B record store {idx, bf16r(f0..f4)}: plain stores (fire-and-
// forget; R8 showed scattered ATOMICS cost ~35B/op memory-side, plain
// stores don't).
__device__ __forceinline__ void scat_feat(int cell, int i,
                                          float f0, float f1, float f2,
                                          float f3, float f4,
                                          const int2* wp2, int* ticket,
                                          int* seg, int S) {
    if (cell < 0) return;
    int w = cell >> 5, b = cell & 31;
    int2 t2 = wp2[w];                   // 8B L2 load (55 KB table, L2-hot)
    int vid = t2.x + __popc(((unsigned)t2.y) & ((1u << b) - 1u));
    if (vid >= MAXV) return;
    int t = atomicAdd(&ticket[(size_t)vid * TPAD], 1);
    if (t < S) {
        int* r = seg + ((size_t)vid * S + t) * RECI;    // 32B-aligned
        int4 a, bb;
        a.x = i;
        a.y = __float_as_int(bf16r(f0));
        a.z = __float_as_int(bf16r(f1));
        a.w = __float_as_int(bf16r(f2));
        bb.x = __float_as_int(bf16r(f3));
        bb.y = __float_as_int(bf16r(f4));
        bb.z = 0; bb.w = 0;
        ((int4*)r)[0] = a;
        ((int4*)r)[1] = bb;
    }
}

// Scatter: 8 pts/thread read CONTIGUOUSLY (10x float4, coalesced, L3-hot),
// cells recomputed (no cellid array), 8 independent lookup->atomic->store
// chains. Features travel inside the seg records so k_fill never gathers.
__global__ __launch_bounds__(256) void k_scatter(const float* pts,
                                                 const int2* wp2, int* ticket,
                                                 int* seg, int S, int n) {
    int g = blockIdx.x * 256 + threadIdx.x;
    int n8 = n >> 3;
    if (g < n8) {
        const float4* p4 = (const float4*)pts;
        float4 r[10];
        #pragma unroll
        for (int k = 0; k < 10; ++k) r[k] = p4[(size_t)g * 10 + k];
        int i0 = g * 8;
        #pragma unroll
        for (int j = 0; j < 8; ++j) {
            float x  = fget(r, 5 * j + 0), y  = fget(r, 5 * j + 1);
            float z  = fget(r, 5 * j + 2), w3 = fget(r, 5 * j + 3);
            float w4 = fget(r, 5 * j + 4);
            int c = cell_of(x, y, z);
            scat_feat(c, i0 + j, x, y, z, w3, w4, wp2, ticket, seg, S);
        }
    }
    if (g == 0) {                       // tail (n % 8 != 0)
        for (int i = n8 * 8; i < n; ++i) {
            const float* p = pts + (size_t)i * 5;
            int c = cell_of(p[0], p[1], p[2]);
            scat_feat(c, i, p[0], p[1], p[2], p[3], p[4], wp2, ticket, seg, S);
        }
    }
}

// One wave per voxel, 8 voxels per 512-thread block (5000 blocks): read
// records COALESCED (2x int4/lane), rank by original index via shfl (stable),
// stage by rank in LDS, block-wide float4 stream-out.
__global__ __launch_bounds__(512) void k_fill(const int* ticket, const int* seg,
                                              int S, float* out_vox, float* out_np) {
    __shared__ float feats[FVOX * MAXP * 5];    // 5 KB staging (8 vox x 160 f)
    __shared__ float npst[FVOX];
    int wave = threadIdx.x >> 6, lane = threadIdx.x & 63;
    int v = blockIdx.x * FVOX + wave;  // MAXV % 8 == 0 -> always in range
    int ntot = ticket[(size_t)v * TPAD];
    int nn = min(ntot, S);             // S >= 32; P(cell count > S) ~ 0
    int m = min(nn, MAXP);
    int myidx = 0x7fffffff;
    float f0 = 0.f, f1 = 0.f, f2 = 0.f, f3 = 0.f, f4 = 0.f;
    if (lane < nn) {
        const int4* rp = (const int4*)(seg + ((size_t)v * S + lane) * RECI);
        int4 a = rp[0], b = rp[1];
        myidx = a.x;
        f0 = __int_as_float(a.y); f1 = __int_as_float(a.z);
        f2 = __int_as_float(a.w);
        f3 = __int_as_float(b.x); f4 = __int_as_float(b.y);
    }
    int rank = 0;
    for (int j = 0; j < nn; ++j) {
        int ej = __shfl(myidx, j, 64);
        rank += (ej < myidx) ? 1 : 0;
    }
    // zero staging, then rank-scatter: both per-wave regions, LDS is
    // program-ordered within a wave -> no barrier needed between them
    if (lane < MAXP) {
        float* d = feats + (wave * MAXP + lane) * 5;
        d[0] = d[1] = d[2] = d[3] = d[4] = 0.0f;
    }
    if (lane < nn && rank < MAXP) {
        float* d = feats + (wave * MAXP + rank) * 5;   // stride 5: conflict-free
        d[0] = f0; d[1] = f1; d[2] = f2; d[3] = f3; d[4] = f4;
    }
    if (lane == 0) npst[wave] = bf16r((float)m);
    __syncthreads();
    // coalesced block output: 8 voxels x 160 floats = 320 float4 per block
    float4* dst4 = (float4*)(out_vox + (size_t)blockIdx.x * (FVOX * MAXP * 5));
    const float4* s4 = (const float4*)feats;
    #pragma unroll
    for (int i = threadIdx.x; i < FVOX * MAXP * 5 / 4; i += 512)
        dst4[i] = s4[i];
    if (threadIdx.x < FVOX)
        out_np[blockIdx.x * FVOX + threadIdx.x] = npst[threadIdx.x];
}

extern "C" void kernel_launch(void* const* d_in, const int* in_sizes, int n_in,
                              void* d_out, int out_size, void* d_ws, size_t ws_size,
                              hipStream_t stream) {
    const float* pts = (const float*)d_in[0];
    int n = in_sizes[0] / 5;

    float* out = (float*)d_out;   // fp32 storage, bf16-precision values
    float* out_vox    = out;                                   // MAXV*32*5
    float* out_coords = out + (size_t)MAXV * MAXP * 5;         // MAXV*3
    float* out_np     = out_coords + (size_t)MAXV * 3;         // MAXV

    // ws ints: cellflag[NFLAGI] + ticket[MAXV*TPAD] + wp2[2*NWORDS]
    //          + seg[MAXV*S*RECI]
    size_t ws_ints = ws_size / sizeof(int);
    const size_t fixed = (size_t)NFLAGI + (size_t)MAXV * TPAD + 2 * (size_t)NWORDS;
    int S = 32;
    {
        auto fits = [&](int s) {
            return fixed + (size_t)MAXV * s * RECI <= ws_ints;
        };
        const int scand[] = {64, 48, 32};
        for (int s : scand) { if (fits(s)) { S = s; break; } }
    }

    int* ws = (int*)d_ws;
    unsigned* cellflag = (unsigned*)ws;                                // NFLAGI ints
    int* ticket        = (int*)(cellflag + NFLAGI);                    // MAXV*TPAD
    int2* wp2          = (int2*)(ticket + (size_t)MAXV * TPAD);        // NWORDS (8B-aligned)
    int* seg           = (int*)(wp2 + NWORDS);                         // MAXV*S*RECI (32B-aligned)

    int nb8 = (n / 8 + 255) / 256;
    if (nb8 < 1) nb8 = 1;
    k_zero<<<ZEROB, 256, 0, stream>>>(cellflag, ticket);
    k_cell<<<CELLG, 1024, 0, stream>>>(pts, (unsigned char*)cellflag, n);
    k_scan<<<SCANB, 256, 0, stream>>>(cellflag, wp2, out_coords);
    k_scatter<<<nb8, 256, 0, stream>>>(pts, wp2, ticket, seg, S, n);
    k_fill<<<MAXV / FVOX, 512, 0, stream>>>(ticket, seg, S, out_vox, out_np);
}

// Round 15
// 138.740 us; speedup vs baseline: 1.0251x; 1.0251x over previous
//
#include <hip/hip_runtime.h>
#include <hip/hip_bf16.h>

#define NXC 440
#define NYC 500
#define GCELLS (NXC * NYC)              // 220000 (NZ = 1)
#define NWORDS ((GCELLS + 31) / 32)     // 6875 bitmap words (6875*32 == 220000)
#define MAXV 40000
#define MAXP 32
#define SCANB ((NWORDS + 255) / 256)    // 27 blocks for word-sliced scan
#define TPAD 16                         // ticket stride (ints): 1 counter / 64B line
                                        // (R14: TPAD=4 regressed +3.8us -- line-level
                                        //  atomic collisions; keep 1 counter/line)
#define CELLG 512                       // k_cell blocks (1024 thr, streaming)
#define ZEROB 128                       // k_zero blocks (cellflag + ticket)
#define NFLAGI (GCELLS / 4)             // cellflag as ints (220000 % 16 == 0)
#define RECI 8                          // seg record stride (ints): idx + 5 feats, 32B

// Expected outputs are bf16-quantized but stored as fp32: round-trip.
__device__ __forceinline__ float bf16r(float x) {
    return __bfloat162float(__float2bfloat16(x));
}

// Linear cell index exactly as the reference (fp32 ops). Invalid -> -1.
__device__ __forceinline__ int cell_of(float x, float y, float z) {
    bool valid = (x >= 0.0f) && (x < 70.4f) &&
                 (y >= -40.0f) && (y < 40.0f) &&
                 (z >= -3.0f) && (z < 1.0f);
    if (!valid) return -1;
    int cx = (int)floorf(x / 0.16f);
    int cy = (int)floorf((y + 40.0f) / 0.16f);
    // z in [-3,1) -> cz == 0 always (NZ = 1)
    cx = min(max(cx, 0), NXC - 1);
    cy = min(max(cy, 0), NYC - 1);
    return cy * NXC + cx;
}

// LSBs of the 4 bytes of u -> nibble (byte j -> bit j).
__device__ __forceinline__ unsigned nib4(unsigned u) {
    return (u | (u >> 7) | (u >> 14) | (u >> 21)) & 0xFu;
}

// Static-index access into a float4[10] register block (unroll-only: i must
// fold to a constant so SROA keeps it in VGPRs -- no scratch).
__device__ __forceinline__ float fget(const float4 (&r)[10], int i) {
    switch (i & 3) {
        case 0:  return r[i >> 2].x;
        case 1:  return r[i >> 2].y;
        case 2:  return r[i >> 2].z;
        default: return r[i >> 2].w;
    }
}

// Zero cellflag (220 KB) + ticket (2.5 MB); both consumed downstream.
__global__ __launch_bounds__(256) void k_zero(unsigned* cellflag, int* ticket) {
    int tid = blockIdx.x * 256 + threadIdx.x;
    int stride = ZEROB * 256;
    uint4* f4 = (uint4*)cellflag;
    for (int i = tid; i < NFLAGI / 4; i += stride)
        f4[i] = make_uint4(0u, 0u, 0u, 0u);
    int4* t4 = (int4*)ticket;
    for (int i = tid; i < MAXV * TPAD / 4; i += stride)
        t4[i] = make_int4(0, 0, 0, 0);
}

// Pass 1: pure flag stream -- plain byte store cellflag[cell]=1 (idempotent
// race; byte-granular dirty masks, verified R10-R12 absmax=0). No cellid
// write: k_scatter recomputes cells from pts (L3-hot re-read).
__global__ __launch_bounds__(1024) void k_cell(const float* pts,
                                               unsigned char* cellflag, int n) {
    int tid = blockIdx.x * 1024 + threadIdx.x;
    int nq = n >> 2;                    // groups of 4 points
    int stride = CELLG * 1024;
    const float4* p4 = (const float4*)pts;
    for (int q = tid; q < nq; q += stride) {
        float4 f0 = p4[q * 5 + 0];      // floats 0..3   (pt0 xyzw0)
        float4 f1 = p4[q * 5 + 1];      // floats 4..7
        float4 f2 = p4[q * 5 + 2];      // floats 8..11
        float4 f3 = p4[q * 5 + 3];      // floats 12..15
        float4 f4 = p4[q * 5 + 4];      // floats 16..19
        int c0 = cell_of(f0.x, f0.y, f0.z);   // floats 0,1,2
        int c1 = cell_of(f1.y, f1.z, f1.w);   // floats 5,6,7
        int c2 = cell_of(f2.z, f2.w, f3.x);   // floats 10,11,12
        int c3 = cell_of(f3.w, f4.x, f4.y);   // floats 15,16,17
        if (c0 >= 0) cellflag[c0] = 1;
        if (c1 >= 0) cellflag[c1] = 1;
        if (c2 >= 0) cellflag[c2] = 1;
        if (c3 >= 0) cellflag[c3] = 1;
    }
    // tail (n % 4 != 0): handled scalar by one thread
    if (tid == 0) {
        for (int i = nq * 4; i < n; ++i) {
            const float* p = pts + (size_t)i * 5;
            int c = cell_of(p[0], p[1], p[2]);
            if (c >= 0) cellflag[c] = 1;
        }
    }
}

// Word-level exclusive scan over the byte-flag array (packed 32 bytes ->
// 1 word on the fly). Self-computed cross-block base -> fused
// (prefix, occword) int2 table; emit coords.
__global__ __launch_bounds__(256) void k_scan(const unsigned* cellflag,
                                              int2* wp2, float* out_coords) {
    int b = blockIdx.x, t = threadIdx.x;
    // cross-block base: count of set flags before this block's slice
    __shared__ int sb[256];
    int pre = 0;
    const uint4* f4 = (const uint4*)cellflag;   // 16 cells per uint4
    for (int i = t; i < b * 512; i += 256) {    // b*512 uint4 = b*256 words
        uint4 v = f4[i];
        unsigned s = v.x + v.y + v.z + v.w;     // per-byte sums <= 4: no carry
        pre += (int)((s * 0x01010101u) >> 24);  // sum of 4 byte-sums
    }
    sb[t] = pre;
    __syncthreads();
    for (int d = 128; d > 0; d >>= 1) {
        if (t < d) sb[t] += sb[t + d];
        __syncthreads();
    }
    int base = sb[0];
    // intra-block scan over this slice
    int w = b * 256 + t;
    unsigned o = 0u;
    if (w < NWORDS) {
        uint4 q0 = f4[w * 2], q1 = f4[w * 2 + 1];   // 32 bytes of word w
        o =  nib4(q0.x)        | (nib4(q0.y) << 4)  |
            (nib4(q0.z) << 8)  | (nib4(q0.w) << 12) |
            (nib4(q1.x) << 16) | (nib4(q1.y) << 20) |
            (nib4(q1.z) << 24) | (nib4(q1.w) << 28);
    }
    int c = __popc(o);
    __shared__ int s[256];
    s[t] = c;
    __syncthreads();
    for (int d = 1; d < 256; d <<= 1) {
        int v = (t >= d) ? s[t - d] : 0;
        __syncthreads();
        s[t] += v;
        __syncthreads();
    }
    int vid = base + (s[t] - c);
    if (w < NWORDS) {
        wp2[w] = make_int2(vid, (int)o);
        if (vid < MAXV) {
            unsigned m = o;
            while (m) {
                int bit = __ffs(m) - 1;
                m &= m - 1u;
                if (vid < MAXV) {
                    int cell = w * 32 + bit;
                    int cy = cell / NXC, cx = cell - cy * NXC;
                    float* oc = out_coords + (size_t)vid * 3;
                    oc[0] = 0.0f;
                    oc[1] = bf16r((float)cy);
                    oc[2] = bf16r((float)cx);
                }
                ++vid;
            }
        }
    }
}

// Ticket + 32B record store {idx, bf16r(f0..f4)}: plain stores (fire-and-
// forget; R8 showed scattered ATOMICS cost ~35B/op memory-side, plain
// stores don't).
__device__ __forceinline__ void scat_feat(int cell, int i,
                                          float f0, float f1, float f2,
                                          float f3, float f4,
                                          const int2* wp2, int* ticket,
                                          int* seg, int S) {
    if (cell < 0) return;
    int w = cell >> 5, b = cell & 31;
    int2 t2 = wp2[w];                   // 8B L2 load (55 KB table, L2-hot)
    int vid = t2.x + __popc(((unsigned)t2.y) & ((1u << b) - 1u));
    if (vid >= MAXV) return;
    int t = atomicAdd(&ticket[(size_t)vid * TPAD], 1);
    if (t < S) {
        int* r = seg + ((size_t)vid * S + t) * RECI;    // 32B-aligned
        int4 a, bb;
        a.x = i;
        a.y = __float_as_int(bf16r(f0));
        a.z = __float_as_int(bf16r(f1));
        a.w = __float_as_int(bf16r(f2));
        bb.x = __float_as_int(bf16r(f3));
        bb.y = __float_as_int(bf16r(f4));
        bb.z = 0; bb.w = 0;
        ((int4*)r)[0] = a;
        ((int4*)r)[1] = bb;
    }
}

// Scatter: 8 pts/thread read CONTIGUOUSLY (10x float4, coalesced, L3-hot),
// cells recomputed (no cellid array), 8 independent lookup->atomic->store
// chains. Features travel inside the seg records so k_fill never gathers.
__global__ __launch_bounds__(256) void k_scatter(const float* pts,
                                                 const int2* wp2, int* ticket,
                                                 int* seg, int S, int n) {
    int g = blockIdx.x * 256 + threadIdx.x;
    int n8 = n >> 3;
    if (g < n8) {
        const float4* p4 = (const float4*)pts;
        float4 r[10];
        #pragma unroll
        for (int k = 0; k < 10; ++k) r[k] = p4[(size_t)g * 10 + k];
        int i0 = g * 8;
        #pragma unroll
        for (int j = 0; j < 8; ++j) {
            float x  = fget(r, 5 * j + 0), y  = fget(r, 5 * j + 1);
            float z  = fget(r, 5 * j + 2), w3 = fget(r, 5 * j + 3);
            float w4 = fget(r, 5 * j + 4);
            int c = cell_of(x, y, z);
            scat_feat(c, i0 + j, x, y, z, w3, w4, wp2, ticket, seg, S);
        }
    }
    if (g == 0) {                       // tail (n % 8 != 0)
        for (int i = n8 * 8; i < n; ++i) {
            const float* p = pts + (size_t)i * 5;
            int c = cell_of(p[0], p[1], p[2]);
            scat_feat(c, i, p[0], p[1], p[2], p[3], p[4], wp2, ticket, seg, S);
        }
    }
}

// One wave per voxel, 4 voxels per 256-thread block: read records COALESCED
// (2x int4/lane), rank by original index via shfl (stable), stage by rank in
// LDS, block-wide float4 stream-out. (R14: 8-vox/512-thr variant regressed.)
__global__ __launch_bounds__(256) void k_fill(const int* ticket, const int* seg,
                                              int S, float* out_vox, float* out_np) {
    __shared__ float feats[4 * MAXP * 5];   // 10 KB staging (4 voxels x 160 f)
    __shared__ float npst[4];
    int wave = threadIdx.x >> 6, lane = threadIdx.x & 63;
    int v = blockIdx.x * 4 + wave;     // MAXV % 4 == 0 -> always in range
    int ntot = ticket[(size_t)v * TPAD];
    int nn = min(ntot, S);             // S >= 32; P(cell count > S) ~ 0
    int m = min(nn, MAXP);
    int myidx = 0x7fffffff;
    float f0 = 0.f, f1 = 0.f, f2 = 0.f, f3 = 0.f, f4 = 0.f;
    if (lane < nn) {
        const int4* rp = (const int4*)(seg + ((size_t)v * S + lane) * RECI);
        int4 a = rp[0], b = rp[1];
        myidx = a.x;
        f0 = __int_as_float(a.y); f1 = __int_as_float(a.z);
        f2 = __int_as_float(a.w);
        f3 = __int_as_float(b.x); f4 = __int_as_float(b.y);
    }
    int rank = 0;
    for (int j = 0; j < nn; ++j) {
        int ej = __shfl(myidx, j, 64);
        rank += (ej < myidx) ? 1 : 0;
    }
    // zero staging, then rank-scatter: both per-wave regions, LDS is
    // program-ordered within a wave -> no barrier needed between them
    if (lane < MAXP) {
        float* d = feats + (wave * MAXP + lane) * 5;
        d[0] = d[1] = d[2] = d[3] = d[4] = 0.0f;
    }
    if (lane < nn && rank < MAXP) {
        float* d = feats + (wave * MAXP + rank) * 5;   // stride 5: conflict-free
        d[0] = f0; d[1] = f1; d[2] = f2; d[3] = f3; d[4] = f4;
    }
    if (lane == 0) npst[wave] = bf16r((float)m);
    __syncthreads();
    // coalesced block output: 4 voxels x 160 floats = 160 float4 per block
    float4* dst4 = (float4*)(out_vox + (size_t)blockIdx.x * (4 * MAXP * 5));
    const float4* s4 = (const float4*)feats;
    #pragma unroll
    for (int i = threadIdx.x; i < 4 * MAXP * 5 / 4; i += 256)
        dst4[i] = s4[i];
    if (threadIdx.x < 4) out_np[blockIdx.x * 4 + threadIdx.x] = npst[threadIdx.x];
}

extern "C" void kernel_launch(void* const* d_in, const int* in_sizes, int n_in,
                              void* d_out, int out_size, void* d_ws, size_t ws_size,
                              hipStream_t stream) {
    const float* pts = (const float*)d_in[0];
    int n = in_sizes[0] / 5;

    float* out = (float*)d_out;   // fp32 storage, bf16-precision values
    float* out_vox    = out;                                   // MAXV*32*5
    float* out_coords = out + (size_t)MAXV * MAXP * 5;         // MAXV*3
    float* out_np     = out_coords + (size_t)MAXV * 3;         // MAXV

    // ws ints: cellflag[NFLAGI] + ticket[MAXV*TPAD] + wp2[2*NWORDS]
    //          + seg[MAXV*S*RECI]
    size_t ws_ints = ws_size / sizeof(int);
    const size_t fixed = (size_t)NFLAGI + (size_t)MAXV * TPAD + 2 * (size_t)NWORDS;
    int S = 32;
    {
        auto fits = [&](int s) {
            return fixed + (size_t)MAXV * s * RECI <= ws_ints;
        };
        const int scand[] = {64, 48, 32};
        for (int s : scand) { if (fits(s)) { S = s; break; } }
    }

    int* ws = (int*)d_ws;
    unsigned* cellflag = (unsigned*)ws;                                // NFLAGI ints
    int* ticket        = (int*)(cellflag + NFLAGI);                    // MAXV*TPAD
    int2* wp2          = (int2*)(ticket + (size_t)MAXV * TPAD);        // NWORDS (8B-aligned)
    int* seg           = (int*)(wp2 + NWORDS);                         // MAXV*S*RECI (32B-aligned)

    int nb8 = (n / 8 + 255) / 256;
    if (nb8 < 1) nb8 = 1;
    k_zero<<<ZEROB, 256, 0, stream>>>(cellflag, ticket);
    k_cell<<<CELLG, 1024, 0, stream>>>(pts, (unsigned char*)cellflag, n);
    k_scan<<<SCANB, 256, 0, stream>>>(cellflag, wp2, out_coords);
    k_scatter<<<nb8, 256, 0, stream>>>(pts, wp2, ticket, seg, S, n);
    k_fill<<<(MAXV + 3) / 4, 256, 0, stream>>>(ticket, seg, S, out_vox, out_np);
}